// Round 4
// baseline (119.635 us; speedup 1.0000x reference)
//
#include <hip/hip_runtime.h>
#include <hip/hip_cooperative_groups.h>
#include <stdint.h>

namespace cg = cooperative_groups;

#define NAC 147456   // 128*128*9
#define NGT 64
#define NB  8
#define APT 3        // anchors per thread in k1 — measured optimum (round 8)
#define BLK 256
#define GX  (NAC / (BLK * APT))   // 192 -> grid 192x8 = 1536 blocks = 6/CU exact

// ---------------- Threefry-2x32 (JAX-compatible, 20 rounds) ----------------
__host__ __device__ static inline uint32_t tf_rotl(uint32_t x, uint32_t d) {
  return (x << d) | (x >> (32u - d));
}

__host__ __device__ static inline void threefry2x32(
    uint32_t k0, uint32_t k1, uint32_t x0, uint32_t x1,
    uint32_t* o0, uint32_t* o1)
{
  const uint32_t ks2 = k0 ^ k1 ^ 0x1BD11BDAu;
  x0 += k0; x1 += k1;
#define TFR(r) { x0 += x1; x1 = tf_rotl(x1, (r)); x1 ^= x0; }
  TFR(13u) TFR(15u) TFR(26u) TFR(6u)   x0 += k1;  x1 += ks2 + 1u;
  TFR(17u) TFR(29u) TFR(16u) TFR(24u)  x0 += ks2; x1 += k0 + 2u;
  TFR(13u) TFR(15u) TFR(26u) TFR(6u)   x0 += k0;  x1 += k1 + 3u;
  TFR(17u) TFR(29u) TFR(16u) TFR(24u)  x0 += k1;  x1 += ks2 + 4u;
  TFR(13u) TFR(15u) TFR(26u) TFR(6u)   x0 += ks2; x1 += k0 + 5u;
#undef TFR
  *o0 = x0; *o1 = x1;
}

__device__ static inline float4 bbox2delta_calc(const float4& a, const float4& g)
{
  const float wr  = a.w - a.y,          hr  = a.z - a.x;
  const float xcr = a.y + 0.5f * wr,    ycr = a.x + 0.5f * hr;
  const float wrc = fmaxf(wr, 1e-5f),   hrc = fmaxf(hr, 1e-5f);
  const float wl  = g.w - g.y,          hl  = g.z - g.x;
  const float xcl = g.y + 0.5f * wl,    ycl = g.x + 0.5f * hl;
  float4 r;
  r.x = fminf(fmaxf((xcl - xcr) / wrc, -10.0f), 10.0f);
  r.y = fminf(fmaxf((ycl - ycr) / hrc, -10.0f), 10.0f);
  r.z = fminf(fmaxf(__logf(wl / wrc),  -10.0f), 10.0f);
  r.w = fminf(fmaxf(__logf(hl / hrc),  -10.0f), 10.0f);
  return r;
}

// ---------------- Fused cooperative kernel -----------------------------------
// Round-13. k1's inner loop is at its VALU floor (emitted insts/IoU ~= source
// 16-18 with the 2-cy wave64 cadence; 80% busy). The remaining addressable
// time is the SECOND DISPATCH: k2 + launch gap + flags write/re-read ~= 29us.
// Fuse via grid-wide sync: 1536 blocks x 256thr @ ~48 VGPR / 1.5KB LDS is
// co-resident (6/CU of >=8 possible), so cg::this_grid().sync() is legal.
//   phase 1 = old k1 (pos/bidx stay in REGISTERS; no flags buffer);
//             per-block pos count -> device atomicAdd(counts[b]).
//   sync    = grid barrier (device-scope fences included).
//   phase 2 = th = 128/(counts[b]+1e-6); per anchor: threefry (exec-masked,
//             ~3% lanes) -> sampled ? bbox2delta : zeros -> out[4..7].
// counts readback uses agent-scope atomic load (per-XCD L2 non-coherence,
// G16). Write volume unchanged (out[4..7] written exactly once either way).
// Inner-loop algebra unchanged from r12 (T-form compare, quad-prefetch,
// bit-identical pos threshold via one IEEE div/anchor in ref rounding order).
__global__ __launch_bounds__(BLK) void k_fused(
    const float* __restrict__ anchors,
    const float* __restrict__ gt,
    const float* __restrict__ deltas,
    float* __restrict__ out,
    int* __restrict__ counts,           // [NB], pre-zeroed
    uint32_t kp0, uint32_t kp1)
{
  __shared__ __align__(16) float4 gbox[NGT];
  __shared__ __align__(16) float  garea[NGT];  // ga_j (exact, epilogue den)
  __shared__ __align__(16) float  gae[NGT];    // ga_j + EPS (T_j in compare)
  __shared__ int s_cnt;
  const int b   = blockIdx.y;
  const int tid = threadIdx.x;

  if (tid == 0) s_cnt = 0;
  if (tid < NGT) {
    float4 g = reinterpret_cast<const float4*>(gt)[b * NGT + tid];
    const float ga = fmaxf(g.z - g.x, 0.0f) * fmaxf(g.w - g.y, 0.0f);
    gbox[tid]  = g;
    garea[tid] = ga;
    gae[tid]   = ga + 1e-5f;
  }
  __syncthreads();

  const int base = blockIdx.x * (BLK * APT) + tid;

  float4 a[APT];
  float  areaA[APT], num[APT], Tb[APT];
  int    bidx[APT];
#pragma unroll
  for (int t = 0; t < APT; ++t) {
    a[t] = reinterpret_cast<const float4*>(anchors)[base + t * BLK];
    areaA[t] = fmaxf(a[t].z - a[t].x, 0.0f) * fmaxf(a[t].w - a[t].y, 0.0f);
    num[t]  = 0.0f;   // incumbent inter
    Tb[t]   = 1.0f;   // incumbent S+e; any >0 gives "update iff inter>0" init
    bidx[t] = 0;
  }

  for (int jj = 0; jj < NGT; jj += 4) {
    const float4 te4 = *reinterpret_cast<const float4*>(&gae[jj]);
    const float4 g0 = gbox[jj + 0];
    const float4 g1 = gbox[jj + 1];
    const float4 g2 = gbox[jj + 2];
    const float4 g3 = gbox[jj + 3];
    const float4 gs[4] = { g0, g1, g2, g3 };
#pragma unroll
    for (int u = 0; u < 4; ++u) {
      const float4 g  = gs[u];
      const float  te = (&te4.x)[u];   // static index after unroll
      const int    j  = jj + u;
#pragma unroll
      for (int t = 0; t < APT; ++t) {
        float yi = fmaxf(a[t].x, g.x);
        float xi = fmaxf(a[t].y, g.y);
        float ya = fminf(a[t].z, g.z);
        float xa = fminf(a[t].w, g.w);
        float inter = fmaxf(ya - yi, 0.0f) * fmaxf(xa - xi, 0.0f);
        float Tj = areaA[t] + te;                 // S_j + EPS, one add
        // iou_j > iou_best  <=>  inter*T_best > num*T_j   (both T > 0)
        bool upd = inter * Tb[t] > num[t] * Tj;
        num[t]  = upd ? inter : num[t];
        Tb[t]   = upd ? Tj    : Tb[t];
        bidx[t] = upd ? j     : bidx[t];
      }
    }
  }

  // ---- phase-1 epilogue: proposals + pos mask (registers) + count ----
  int posm = 0;
  int npos = 0;
#pragma unroll
  for (int t = 0; t < APT; ++t) {
    const int i = base + t * BLK;
    // Exact reference rounding order for the pos test:
    const float gaB = garea[bidx[t]];
    const float den = ((areaA[t] + gaB) - num[t]) + 1e-5f;
    const float best_iou = (10000.0f * num[t]) / den;
    const bool pos = best_iou > 5000.0f;
    posm |= (pos ? 1 : 0) << t;

    const float4 d = reinterpret_cast<const float4*>(deltas)[b * NAC + i];
    const float wb = a[t].w - a[t].y, hb = a[t].z - a[t].x;
    const float xc = a[t].y + 0.5f * wb + wb * d.x;
    const float yc = a[t].x + 0.5f * hb + hb * d.y;
    const float w_ = wb * __expf(d.z);
    const float h_ = hb * __expf(d.w);

    float* rowp = out + ((size_t)b * NAC + i) * 8;
    reinterpret_cast<float4*>(rowp)[0] =
        make_float4(yc - 0.5f * h_, xc - 0.5f * w_, yc + 0.5f * h_, xc + 0.5f * w_);

    unsigned long long m = __ballot(pos);
    if ((tid & 63) == 0) npos += (int)__popcll(m);
  }
  if ((tid & 63) == 0 && npos)
    atomicAdd(&s_cnt, npos);
  __syncthreads();
  if (tid == 0 && s_cnt)
    atomicAdd(&counts[b], s_cnt);     // device-scope

  // ---- grid-wide barrier ----
  cg::this_grid().sync();

  // ---- phase 2: sparse sampling, one 16B store per anchor ----
  const int tot = __hip_atomic_load(&counts[b], __ATOMIC_RELAXED,
                                    __HIP_MEMORY_SCOPE_AGENT);
  const float th = 128.0f / ((float)tot + 1e-6f);

#pragma unroll
  for (int t = 0; t < APT; ++t) {
    const int i = base + t * BLK;
    const int f = b * NAC + i;
    float4 r = make_float4(0.f, 0.f, 0.f, 0.f);
    if ((posm >> t) & 1) {
      uint32_t o0, o1;
      threefry2x32(kp0, kp1, 0u, (uint32_t)f, &o0, &o1);
      const uint32_t bits = o0 ^ o1;
      union { uint32_t u; float flt; } cv;
      cv.u = (bits >> 9) | 0x3F800000u;
      if (cv.flt - 1.0f < th) {
        const float4 g = gbox[bidx[t]];
        r = bbox2delta_calc(a[t], g);
      }
    }
    reinterpret_cast<float4*>(out + (size_t)f * 8)[1] = r;
  }
}

// ---------------- Fallback path (proven two-kernel, flag in out[4]) ----------
__global__ __launch_bounds__(BLK) void k1_classify(
    const float* __restrict__ anchors,
    const float* __restrict__ gt,
    const float* __restrict__ deltas,
    float* __restrict__ out,
    int* __restrict__ counts)
{
  __shared__ __align__(16) float4 gbox[NGT];
  __shared__ __align__(16) float  garea[NGT];
  __shared__ __align__(16) float  gae[NGT];
  __shared__ int s_cnt;
  const int b   = blockIdx.y;
  const int tid = threadIdx.x;

  if (tid == 0) s_cnt = 0;
  if (tid < NGT) {
    float4 g = reinterpret_cast<const float4*>(gt)[b * NGT + tid];
    const float ga = fmaxf(g.z - g.x, 0.0f) * fmaxf(g.w - g.y, 0.0f);
    gbox[tid]  = g;
    garea[tid] = ga;
    gae[tid]   = ga + 1e-5f;
  }
  __syncthreads();

  const int base = blockIdx.x * (BLK * APT) + tid;

  float4 a[APT];
  float  areaA[APT], num[APT], Tb[APT];
  int    bidx[APT];
#pragma unroll
  for (int t = 0; t < APT; ++t) {
    a[t] = reinterpret_cast<const float4*>(anchors)[base + t * BLK];
    areaA[t] = fmaxf(a[t].z - a[t].x, 0.0f) * fmaxf(a[t].w - a[t].y, 0.0f);
    num[t]  = 0.0f;
    Tb[t]   = 1.0f;
    bidx[t] = 0;
  }

  for (int jj = 0; jj < NGT; jj += 4) {
    const float4 te4 = *reinterpret_cast<const float4*>(&gae[jj]);
    const float4 g0 = gbox[jj + 0];
    const float4 g1 = gbox[jj + 1];
    const float4 g2 = gbox[jj + 2];
    const float4 g3 = gbox[jj + 3];
    const float4 gs[4] = { g0, g1, g2, g3 };
#pragma unroll
    for (int u = 0; u < 4; ++u) {
      const float4 g  = gs[u];
      const float  te = (&te4.x)[u];
      const int    j  = jj + u;
#pragma unroll
      for (int t = 0; t < APT; ++t) {
        float yi = fmaxf(a[t].x, g.x);
        float xi = fmaxf(a[t].y, g.y);
        float ya = fminf(a[t].z, g.z);
        float xa = fminf(a[t].w, g.w);
        float inter = fmaxf(ya - yi, 0.0f) * fmaxf(xa - xi, 0.0f);
        float Tj = areaA[t] + te;
        bool upd = inter * Tb[t] > num[t] * Tj;
        num[t]  = upd ? inter : num[t];
        Tb[t]   = upd ? Tj    : Tb[t];
        bidx[t] = upd ? j     : bidx[t];
      }
    }
  }

  int npos = 0;
#pragma unroll
  for (int t = 0; t < APT; ++t) {
    const int i = base + t * BLK;
    const float gaB = garea[bidx[t]];
    const float den = ((areaA[t] + gaB) - num[t]) + 1e-5f;
    const float best_iou = (10000.0f * num[t]) / den;
    const bool pos = best_iou > 5000.0f;

    const float4 d = reinterpret_cast<const float4*>(deltas)[b * NAC + i];
    const float wb = a[t].w - a[t].y, hb = a[t].z - a[t].x;
    const float xc = a[t].y + 0.5f * wb + wb * d.x;
    const float yc = a[t].x + 0.5f * hb + hb * d.y;
    const float w_ = wb * __expf(d.z);
    const float h_ = hb * __expf(d.w);

    float* rowp = out + ((size_t)b * NAC + i) * 8;
    reinterpret_cast<float4*>(rowp)[0] =
        make_float4(yc - 0.5f * h_, xc - 0.5f * w_, yc + 0.5f * h_, xc + 0.5f * w_);
    reinterpret_cast<float4*>(rowp)[1] =
        make_float4(pos ? (float)(bidx[t] + 1) : 0.0f, 0.f, 0.f, 0.f);

    unsigned long long m = __ballot(pos);
    if ((tid & 63) == 0) npos += (int)__popcll(m);
  }
  if ((tid & 63) == 0 && npos)
    atomicAdd(&s_cnt, npos);
  __syncthreads();

  if (tid == 0 && s_cnt) atomicAdd(&counts[b], s_cnt);
}

__global__ __launch_bounds__(256) void k2_fallback(
    const float* __restrict__ anchors,
    const float* __restrict__ gt,
    float* __restrict__ out,
    const int* __restrict__ counts,
    uint32_t kp0, uint32_t kp1)
{
  const int b = blockIdx.y;
  const int i = blockIdx.x * 256 + threadIdx.x;
  const int f = b * NAC + i;
  float* rowp = out + (size_t)f * 8;

  const float flag = rowp[4];
  if (flag == 0.0f) return;

  const float th = 128.0f / ((float)counts[b] + 1e-6f);

  uint32_t o0, o1;
  threefry2x32(kp0, kp1, 0u, (uint32_t)f, &o0, &o1);
  const uint32_t bits = o0 ^ o1;
  union { uint32_t u; float flt; } cv;
  cv.u = (bits >> 9) | 0x3F800000u;

  if (cv.flt - 1.0f < th) {
    const float4 a = reinterpret_cast<const float4*>(anchors)[i];
    const float4 g = reinterpret_cast<const float4*>(gt)[b * NGT + ((int)flag - 1)];
    float4 r = bbox2delta_calc(a, g);
    *reinterpret_cast<float4*>(rowp + 4) = r;
  } else {
    reinterpret_cast<float4*>(rowp)[1] = make_float4(0.f, 0.f, 0.f, 0.f);
  }
}

extern "C" void kernel_launch(void* const* d_in, const int* in_sizes, int n_in,
                              void* d_out, int out_size, void* d_ws, size_t ws_size,
                              hipStream_t stream)
{
  const float* anchors = (const float*)d_in[0];
  const float* gt      = (const float*)d_in[1];
  const float* deltas  = (const float*)d_in[2];
  float* out   = (float*)d_out;
  int* counts  = (int*)d_ws;    // [NB]

  // kp = jax.random.split(jax.random.key(42))[0], threefry_partitionable:
  // kp = threefry2x32((0,42), 0, 0), full pair. (Verified rounds 2/3/5-9.)
  uint32_t kp0, kp1;
  threefry2x32(0u, 42u, 0u, 0u, &kp0, &kp1);

  static int coop_ok = -1;
  if (coop_ok < 0) {
    int dev = 0, c = 0;
    hipGetDevice(&dev);
    hipDeviceGetAttribute(&c, hipDeviceAttributeCooperativeLaunch, dev);
    coop_ok = c;
  }

  hipMemsetAsync(counts, 0, NB * sizeof(int), stream);

  bool launched = false;
  if (coop_ok) {
    void* params[] = { (void*)&anchors, (void*)&gt, (void*)&deltas,
                       (void*)&out, (void*)&counts, (void*)&kp0, (void*)&kp1 };
    hipError_t e = hipLaunchCooperativeKernel(
        reinterpret_cast<void*>(k_fused), dim3(GX, NB), dim3(BLK),
        params, 0, stream);
    launched = (e == hipSuccess);
    if (!launched) coop_ok = 0;   // don't retry the broken path
  }
  if (!launched) {
    dim3 g1(GX, NB);
    k1_classify<<<g1, dim3(BLK), 0, stream>>>(anchors, gt, deltas, out, counts);
    dim3 g2(NAC / 256, NB);
    k2_fallback<<<g2, dim3(256), 0, stream>>>(anchors, gt, out, counts,
                                              kp0, kp1);
  }
}

// Round 5
// 116.729 us; speedup vs baseline: 1.0249x; 1.0249x over previous
//
#include <hip/hip_runtime.h>
#include <stdint.h>

#define NAC 147456   // 128*128*9
#define NGT 64
#define NGTP 72      // padded so the ping-pong prefetch never branches
#define NB  8
#define APT 3        // anchors per thread in k1 — measured optimum (round 8)
#define BLK 256
#define GX  (NAC / (BLK * APT))   // 192 -> grid 192x8 = 1536 blocks = 6/CU exact

// ---------------- Threefry-2x32 (JAX-compatible, 20 rounds) ----------------
__host__ __device__ static inline uint32_t tf_rotl(uint32_t x, uint32_t d) {
  return (x << d) | (x >> (32u - d));
}

__host__ __device__ static inline void threefry2x32(
    uint32_t k0, uint32_t k1, uint32_t x0, uint32_t x1,
    uint32_t* o0, uint32_t* o1)
{
  const uint32_t ks2 = k0 ^ k1 ^ 0x1BD11BDAu;
  x0 += k0; x1 += k1;
#define TFR(r) { x0 += x1; x1 = tf_rotl(x1, (r)); x1 ^= x0; }
  TFR(13u) TFR(15u) TFR(26u) TFR(6u)   x0 += k1;  x1 += ks2 + 1u;
  TFR(17u) TFR(29u) TFR(16u) TFR(24u)  x0 += ks2; x1 += k0 + 2u;
  TFR(13u) TFR(15u) TFR(26u) TFR(6u)   x0 += k0;  x1 += k1 + 3u;
  TFR(17u) TFR(29u) TFR(16u) TFR(24u)  x0 += k1;  x1 += ks2 + 4u;
  TFR(13u) TFR(15u) TFR(26u) TFR(6u)   x0 += ks2; x1 += k0 + 5u;
#undef TFR
  *o0 = x0; *o1 = x1;
}

__device__ static inline void bbox2delta_store(
    const float4& a, const float4& g, float* dst)
{
  const float wr  = a.w - a.y,          hr  = a.z - a.x;
  const float xcr = a.y + 0.5f * wr,    ycr = a.x + 0.5f * hr;
  const float wrc = fmaxf(wr, 1e-5f),   hrc = fmaxf(hr, 1e-5f);
  const float wl  = g.w - g.y,          hl  = g.z - g.x;
  const float xcl = g.y + 0.5f * wl,    ycl = g.x + 0.5f * hl;
  float4 r;
  r.x = fminf(fmaxf((xcl - xcr) / wrc, -10.0f), 10.0f);
  r.y = fminf(fmaxf((ycl - ycr) / hrc, -10.0f), 10.0f);
  r.z = fminf(fmaxf(__logf(wl / wrc),  -10.0f), 10.0f);
  r.w = fminf(fmaxf(__logf(hl / hrc),  -10.0f), 10.0f);
  *reinterpret_cast<float4*>(dst) = r;
}

// ---------------- Kernel 1: IoU argmax + proposals + flags + block count -----
// Round-14. History (counter-driven):
//   r10 div-free:                    43.3us @ 81% VALUBusy
//   r11 SMEM g in loop:              44.0us @ 72% (lgkmcnt poisoning - reverted)
//   r12 T-form + quad-prefetch:      ~43us  (marginal)
//   r13 coop-fusion:                 FAILED +3.4us total (launch-path overhead;
//       compute itself <=43us). Reverted to two-kernel.
// Source op count is 17 VALU/IoU = 16.3us floor @ 100% issue; measured 43.
// Either allocator-mov bloat (44-VGPR squeeze) or VALUBusy is overstated by
// the gfx94x formula fallback and we are LDS/dep-stall-bound. Both fixes:
//   (a) ping-pong software pipeline: prefetch group jj+4's 5x ds_read_b128
//       into B-registers while computing group jj from A-registers; unroll-2
//       so buffers alternate with NO swap movs; gbox/gae padded to 72 so the
//       tail prefetch needs no branch (pad values loaded, never consumed).
//   (b) __launch_bounds__(BLK,4): VGPR ceiling 128 (vs compiler's 44-reg
//       squeeze) - headroom for ~80-reg pipelined state without movs/spills.
//       Actual use ~80 still fits 6 blocks/CU physically. (Round-7's failure
//       was a TIGHT cap forcing spills; this RAISES the ceiling.)
// Inner-loop algebra unchanged from r12 (T-form compare; bit-identical pos
// threshold via one IEEE div/anchor in reference rounding order).
// FETCH_SIZE is the spill canary: ~10.4MB expected; any jump = scratch.
template <bool USE_FLAGS>
__global__ __launch_bounds__(BLK, 4) void k1_classify(
    const float* __restrict__ anchors,
    const float* __restrict__ gt,
    const float* __restrict__ deltas,
    float* __restrict__ out,
    int* __restrict__ cnt_blk,          // USE_FLAGS: [NB*GX]; else counts[NB]
    unsigned char* __restrict__ flags)
{
  __shared__ __align__(16) float4 gbox[NGTP];
  __shared__ __align__(16) float  garea[NGT];   // ga_j (exact, epilogue den)
  __shared__ __align__(16) float  gae[NGTP];    // ga_j + EPS (T_j in compare)
  __shared__ int s_cnt;
  const int b   = blockIdx.y;
  const int tid = threadIdx.x;

  if (tid == 0) s_cnt = 0;
  if (tid < NGTP) {
    if (tid < NGT) {
      float4 g = reinterpret_cast<const float4*>(gt)[b * NGT + tid];
      const float ga = fmaxf(g.z - g.x, 0.0f) * fmaxf(g.w - g.y, 0.0f);
      gbox[tid]  = g;
      garea[tid] = ga;
      gae[tid]   = ga + 1e-5f;
    } else {
      gbox[tid] = make_float4(0.f, 0.f, 0.f, 0.f);   // pad: loaded, never used
      gae[tid]  = 0.f;
    }
  }
  __syncthreads();

  const int base = blockIdx.x * (BLK * APT) + tid;

  float4 a[APT];
  float  areaA[APT], num[APT], Tb[APT];
  int    bidx[APT];
#pragma unroll
  for (int t = 0; t < APT; ++t) {
    a[t] = reinterpret_cast<const float4*>(anchors)[base + t * BLK];
    areaA[t] = fmaxf(a[t].z - a[t].x, 0.0f) * fmaxf(a[t].w - a[t].y, 0.0f);
    num[t]  = 0.0f;   // incumbent inter
    Tb[t]   = 1.0f;   // incumbent S+e; any >0 gives "update iff inter>0" init
    bidx[t] = 0;
  }

  // One j-step against gt box g with precomputed te = ga_j + EPS.
#define IOU_ONE(gv, te, jv)                                              \
  {                                                                      \
    const float4 g_ = (gv);                                              \
    const float  te_ = (te);                                             \
    const int    j_  = (jv);                                             \
    _Pragma("unroll")                                                    \
    for (int t = 0; t < APT; ++t) {                                      \
      float yi = fmaxf(a[t].x, g_.x);                                    \
      float xi = fmaxf(a[t].y, g_.y);                                    \
      float ya = fminf(a[t].z, g_.z);                                    \
      float xa = fminf(a[t].w, g_.w);                                    \
      float inter = fmaxf(ya - yi, 0.0f) * fmaxf(xa - xi, 0.0f);         \
      float Tj = areaA[t] + te_;                                         \
      bool upd = inter * Tb[t] > num[t] * Tj;                            \
      num[t]  = upd ? inter : num[t];                                    \
      Tb[t]   = upd ? Tj    : Tb[t];                                     \
      bidx[t] = upd ? j_    : bidx[t];                                   \
    }                                                                    \
  }

  // Ping-pong pipelined over 4-j groups: load B(jj+4) || compute A(jj),
  // then load A(jj+8) || compute B(jj+4). Pads make the tail branch-free.
  float4 teA = *reinterpret_cast<const float4*>(&gae[0]);
  float4 gA0 = gbox[0], gA1 = gbox[1], gA2 = gbox[2], gA3 = gbox[3];

  for (int jj = 0; jj < NGT; jj += 8) {
    float4 teB = *reinterpret_cast<const float4*>(&gae[jj + 4]);
    float4 gB0 = gbox[jj + 4], gB1 = gbox[jj + 5],
           gB2 = gbox[jj + 6], gB3 = gbox[jj + 7];

    IOU_ONE(gA0, teA.x, jj + 0)
    IOU_ONE(gA1, teA.y, jj + 1)
    IOU_ONE(gA2, teA.z, jj + 2)
    IOU_ONE(gA3, teA.w, jj + 3)

    teA = *reinterpret_cast<const float4*>(&gae[jj + 8]);   // pad-safe
    gA0 = gbox[jj + 8];  gA1 = gbox[jj + 9];
    gA2 = gbox[jj + 10]; gA3 = gbox[jj + 11];

    IOU_ONE(gB0, teB.x, jj + 4)
    IOU_ONE(gB1, teB.y, jj + 5)
    IOU_ONE(gB2, teB.z, jj + 6)
    IOU_ONE(gB3, teB.w, jj + 7)
  }
#undef IOU_ONE

  int npos = 0;
#pragma unroll
  for (int t = 0; t < APT; ++t) {
    const int i = base + t * BLK;
    // Exact reference rounding order for the pos test:
    // den = ((areaA + ga_best) - inter_best) + EPS ; iou = (10000*inter)/den
    const float gaB = garea[bidx[t]];
    const float den = ((areaA[t] + gaB) - num[t]) + 1e-5f;
    const float best_iou = (10000.0f * num[t]) / den;
    const bool pos = best_iou > 5000.0f;

    const float4 d = reinterpret_cast<const float4*>(deltas)[b * NAC + i];
    const float wb = a[t].w - a[t].y, hb = a[t].z - a[t].x;
    const float xc = a[t].y + 0.5f * wb + wb * d.x;
    const float yc = a[t].x + 0.5f * hb + hb * d.y;
    const float w_ = wb * __expf(d.z);
    const float h_ = hb * __expf(d.w);

    float* rowp = out + ((size_t)b * NAC + i) * 8;
    reinterpret_cast<float4*>(rowp)[0] =
        make_float4(yc - 0.5f * h_, xc - 0.5f * w_, yc + 0.5f * h_, xc + 0.5f * w_);
    if (USE_FLAGS) {
      reinterpret_cast<float4*>(rowp)[1] = make_float4(0.f, 0.f, 0.f, 0.f);
      flags[(size_t)b * NAC + i] = pos ? (unsigned char)(bidx[t] + 1) : 0u;
    } else {
      reinterpret_cast<float4*>(rowp)[1] =
          make_float4(pos ? (float)(bidx[t] + 1) : 0.0f, 0.f, 0.f, 0.f);
    }

    unsigned long long m = __ballot(pos);
    if ((tid & 63) == 0) npos += (int)__popcll(m);
  }
  if ((tid & 63) == 0 && npos)
    atomicAdd(&s_cnt, npos);
  __syncthreads();

  if (tid == 0) {
    if (USE_FLAGS) cnt_blk[b * GX + blockIdx.x] = s_cnt;  // written once, no memset
    else if (s_cnt) atomicAdd(&cnt_blk[b], s_cnt);
  }
}

// ---------------- Kernel 2a (flags): sum block counts, sparse sampling -------
__global__ __launch_bounds__(256) void k2_flags(
    const float* __restrict__ anchors,
    const float* __restrict__ gt,
    float* __restrict__ out,
    const int* __restrict__ cnt_blk,
    const unsigned char* __restrict__ flags,
    uint32_t kp0, uint32_t kp1)
{
  __shared__ int s_tot;
  const int b   = blockIdx.y;
  const int tid = threadIdx.x;

  if (tid == 0) s_tot = 0;
  __syncthreads();
  if (tid < GX) atomicAdd(&s_tot, cnt_blk[b * GX + tid]);
  __syncthreads();
  const float th = 128.0f / ((float)s_tot + 1e-6f);

  const int chunk = blockIdx.x * 256 + tid;   // 16 rows per thread
  uint4 fv = reinterpret_cast<const uint4*>(flags + (size_t)b * NAC)[chunk];
  if ((fv.x | fv.y | fv.z | fv.w) == 0u) return;

  const uint32_t words[4] = { fv.x, fv.y, fv.z, fv.w };
  const int base_i = chunk * 16;

#pragma unroll
  for (int w = 0; w < 4; ++w) {
    uint32_t wd = words[w];
    while (wd) {
      const int byte = __ffs(wd) / 8;        // flag <= 64 keeps byte MSB clear
      const int fl   = (wd >> (byte * 8)) & 0xFF;
      wd &= ~(0xFFu << (byte * 8));
      const int i = base_i + w * 4 + byte;
      const int f = b * NAC + i;

      uint32_t o0, o1;
      threefry2x32(kp0, kp1, 0u, (uint32_t)f, &o0, &o1);
      const uint32_t bits = o0 ^ o1;
      union { uint32_t u; float flt; } cv;
      cv.u = (bits >> 9) | 0x3F800000u;
      if (cv.flt - 1.0f < th) {
        const float4 a = reinterpret_cast<const float4*>(anchors)[i];
        const float4 g = reinterpret_cast<const float4*>(gt)[b * NGT + (fl - 1)];
        bbox2delta_store(a, g, out + (size_t)f * 8 + 4);
      }
    }
  }
}

// ---------------- Kernel 2b (fallback, proven): flag in out[4] ---------------
__global__ __launch_bounds__(256) void k2_fallback(
    const float* __restrict__ anchors,
    const float* __restrict__ gt,
    float* __restrict__ out,
    const int* __restrict__ counts,
    uint32_t kp0, uint32_t kp1)
{
  const int b = blockIdx.y;
  const int i = blockIdx.x * 256 + threadIdx.x;
  const int f = b * NAC + i;
  float* rowp = out + (size_t)f * 8;

  const float flag = rowp[4];
  if (flag == 0.0f) return;

  const float th = 128.0f / ((float)counts[b] + 1e-6f);

  uint32_t o0, o1;
  threefry2x32(kp0, kp1, 0u, (uint32_t)f, &o0, &o1);
  const uint32_t bits = o0 ^ o1;
  union { uint32_t u; float flt; } cv;
  cv.u = (bits >> 9) | 0x3F800000u;

  if (cv.flt - 1.0f < th) {
    const float4 a = reinterpret_cast<const float4*>(anchors)[i];
    const float4 g = reinterpret_cast<const float4*>(gt)[b * NGT + ((int)flag - 1)];
    bbox2delta_store(a, g, rowp + 4);
  } else {
    reinterpret_cast<float4*>(rowp)[1] = make_float4(0.f, 0.f, 0.f, 0.f);
  }
}

extern "C" void kernel_launch(void* const* d_in, const int* in_sizes, int n_in,
                              void* d_out, int out_size, void* d_ws, size_t ws_size,
                              hipStream_t stream)
{
  const float* anchors = (const float*)d_in[0];
  const float* gt      = (const float*)d_in[1];
  const float* deltas  = (const float*)d_in[2];
  float* out  = (float*)d_out;
  int* cnt_blk = (int*)d_ws;                                // [NB*GX] ints
  unsigned char* flags = (unsigned char*)d_ws + 8192;       // [NB*NAC] bytes

  const bool use_flags = ws_size >= (size_t)(8192 + NB * NAC);

  // kp = jax.random.split(jax.random.key(42))[0], threefry_partitionable:
  // kp = threefry2x32((0,42), 0, 0), full pair. (Verified rounds 2/3/5-9.)
  uint32_t kp0, kp1;
  threefry2x32(0u, 42u, 0u, 0u, &kp0, &kp1);

  dim3 g1(GX, NB);   // (192, 8) = 1536 blocks, 6/CU exact
  if (use_flags) {
    k1_classify<true><<<g1, dim3(BLK), 0, stream>>>(anchors, gt, deltas, out,
                                                    cnt_blk, flags);
    dim3 g2(NAC / 16 / 256, NB);   // (36, 8)
    k2_flags<<<g2, dim3(256), 0, stream>>>(anchors, gt, out, cnt_blk, flags,
                                           kp0, kp1);
  } else {
    hipMemsetAsync(cnt_blk, 0, NB * sizeof(int), stream);
    k1_classify<false><<<g1, dim3(BLK), 0, stream>>>(anchors, gt, deltas, out,
                                                     cnt_blk, nullptr);
    dim3 g2(NAC / 256, NB);        // (576, 8)
    k2_fallback<<<g2, dim3(256), 0, stream>>>(anchors, gt, out, cnt_blk,
                                              kp0, kp1);
  }
}